// Round 1
// baseline (168.410 us; speedup 1.0000x reference)
//
#include <hip/hip_runtime.h>

#define S   4
#define BB  8
#define CC  64
#define HH  128
#define WW  256
#define KC  8            // channels per LDS chunk
#define TH  8            // rows per block
#define TW  64           // cols per block
#define TROWS 16         // TH + 2S
#define PITCH 72         // TW + 2S

// Map displacement (di,dj) -> output index in the reference's enumeration order.
__device__ constexpr int ord_idx(int di, int dj) {
  int i = di < 0 ? -di : di;
  int j = dj < 0 ? -dj : dj;
  if (i == 0 && j == 0) return 0;
  if (j == 0) return 1 + (i - 1) * 20 + (di > 0 ? 0 : 1);
  if (i == 0) return 1 + (j - 1) * 20 + (dj > 0 ? 2 : 3);
  return 1 + (i - 1) * 20 + 4 + (j - 1) * 4 +
         (di > 0 ? (dj > 0 ? 0 : 2) : (dj > 0 ? 1 : 3));
}

__global__ __launch_bounds__(256, 2)
void costvol_kernel(const float* __restrict__ src,
                    const float* __restrict__ tgt,
                    float* __restrict__ out) {
  __shared__ __align__(16) float lds[KC][TROWS][PITCH];

  const int tx  = threadIdx.x;            // 0..31
  const int ty  = threadIdx.y;            // 0..7
  const int tid = ty * 32 + tx;           // 0..255
  const int bx  = blockIdx.x;             // 0..3
  const int by  = blockIdx.y;             // 0..15
  const int b   = blockIdx.z;             // 0..7

  const int w0b = bx * TW;
  const int h0  = by * TH;
  const int h   = h0 + ty;
  const int w0  = w0b + tx * 2;           // even -> float2/b64 aligned

  float acc[81][2];
#pragma unroll
  for (int o = 0; o < 81; ++o) { acc[o][0] = 0.f; acc[o][1] = 0.f; }

  for (int c0 = 0; c0 < CC; c0 += KC) {
    __syncthreads();   // protect LDS against readers of previous chunk

    // ---- stage tgt chunk into LDS, zero-padded halo, all bounds here ----
    // KC*TROWS*PITCH = 9216 floats = 2304 float4 = 9 per thread.
    // PITCH=72 = 18 float4; halo quads (cq==0, cq==17) are exactly 4-aligned.
#pragma unroll
    for (int k = 0; k < 9; ++k) {
      const int f4  = tid + k * 256;          // 0..2303
      const int c   = f4 / 288;               // 288 = TROWS*18
      const int rem = f4 - c * 288;
      const int r   = rem / 18;
      const int cq  = rem - r * 18;
      const int gh  = h0 - S + r;
      const int gw  = w0b - S + cq * 4;
      float4 v = make_float4(0.f, 0.f, 0.f, 0.f);
      if ((unsigned)gh < (unsigned)HH && gw >= 0 && gw + 3 < WW) {
        v = *reinterpret_cast<const float4*>(
              tgt + (((size_t)b * CC + (c0 + c)) * HH + gh) * WW + gw);
      }
      *reinterpret_cast<float4*>(&lds[c][r][cq * 4]) = v;
    }

    // ---- src chunk lives in registers across the whole di loop ----
    float srcv[KC][2];
#pragma unroll
    for (int c = 0; c < KC; ++c) {
      const float2 s2 = *reinterpret_cast<const float2*>(
          src + (((size_t)b * CC + (c0 + c)) * HH + h) * WW + w0);
      srcv[c][0] = s2.x; srcv[c][1] = s2.y;
    }

    __syncthreads();

    // ---- compute: 9 di x KC c x (5 ds_read_b64 + 18 FMA) ----
#pragma unroll
    for (int di = -S; di <= S; ++di) {
      const int row = ty + S - di;          // in [ty, ty+8] subset of [0,15]
#pragma unroll
      for (int c = 0; c < KC; ++c) {
        const float2* rp =
            reinterpret_cast<const float2*>(&lds[c][row][tx * 2]);
        float win[10];
#pragma unroll
        for (int k = 0; k < 5; ++k) {
          const float2 t = rp[k];
          win[2 * k]     = t.x;
          win[2 * k + 1] = t.y;
        }
#pragma unroll
        for (int dj = -S; dj <= S; ++dj) {
          const int o = ord_idx(di, dj);    // compile-time constant
          acc[o][0] += srcv[c][0] * win[0 + S - dj];
          acc[o][1] += srcv[c][1] * win[1 + S - dj];
        }
      }
    }
  }

  // ---- store: 81 coalesced float2 stores per thread ----
  const size_t HW = (size_t)HH * WW;
  float* op = out + (size_t)b * 81 * HW + (size_t)h * WW + w0;
#pragma unroll
  for (int o = 0; o < 81; ++o) {
    *reinterpret_cast<float2*>(op + (size_t)o * HW) =
        make_float2(acc[o][0], acc[o][1]);
  }
}

extern "C" void kernel_launch(void* const* d_in, const int* in_sizes, int n_in,
                              void* d_out, int out_size, void* d_ws, size_t ws_size,
                              hipStream_t stream) {
  const float* src = (const float*)d_in[0];
  const float* tgt = (const float*)d_in[1];
  float* out = (float*)d_out;
  // search_range (d_in[2]) is fixed at 4 per setup_inputs; geometry hardcoded.
  dim3 grid(WW / TW, HH / TH, BB);   // (4, 16, 8)
  dim3 block(32, 8, 1);
  costvol_kernel<<<grid, block, 0, stream>>>(src, tgt, out);
}

// Round 2
// 97.058 us; speedup vs baseline: 1.7351x; 1.7351x over previous
//
#include <hip/hip_runtime.h>

#define S   4
#define BB  8
#define CC  64
#define HH  128
#define WW  256
#define KC  8            // channels per LDS chunk
#define TH  8            // rows per block
#define TW  64           // cols per block
#define TROWS 16         // TH + 2S
#define PITCH 72         // TW + 2S
#define NGRP 3           // di groups: {-4..-2}, {-1..1}, {2..4}
#define NT   768         // 32 * 8 * 3

// Map displacement (di,dj) -> output index in the reference's enumeration order.
__device__ constexpr int ord_idx(int di, int dj) {
  int i = di < 0 ? -di : di;
  int j = dj < 0 ? -dj : dj;
  if (i == 0 && j == 0) return 0;
  if (j == 0) return 1 + (i - 1) * 20 + (di > 0 ? 0 : 1);
  if (i == 0) return 1 + (j - 1) * 20 + (dj > 0 ? 2 : 3);
  return 1 + (i - 1) * 20 + 4 + (j - 1) * 4 +
         (di > 0 ? (dj > 0 ? 0 : 2) : (dj > 0 ? 1 : 3));
}

__global__ __launch_bounds__(NT, 2)
void costvol_kernel(const float* __restrict__ src,
                    const float* __restrict__ tgt,
                    float* __restrict__ out) {
  __shared__ __align__(16) float lds[KC][TROWS][PITCH];

  const int tx  = threadIdx.x;            // 0..31
  const int ty  = threadIdx.y;            // 0..7  (row within tile)
  const int tz  = threadIdx.z;            // 0..2  (di group)
  const int tid = tz * 256 + ty * 32 + tx;
  const int bx  = blockIdx.x;             // 0..3
  const int by  = blockIdx.y;             // 0..15
  const int b   = blockIdx.z;             // 0..7

  const int w0b = bx * TW;
  const int h0  = by * TH;
  const int h   = h0 + ty;
  const int w0  = w0b + tx * 2;           // even -> float2/b64 aligned
  const int di_base = tz * 3 - S;         // -4, -1, 2 (wave-uniform)

  // 27 displacements per group, 2 pixels each -> 54 accumulator VGPRs.
  float acc[27][2];
#pragma unroll
  for (int o = 0; o < 27; ++o) { acc[o][0] = 0.f; acc[o][1] = 0.f; }

  for (int c0 = 0; c0 < CC; c0 += KC) {
    __syncthreads();   // protect LDS against readers of previous chunk

    // ---- stage tgt chunk into LDS, zero-padded halo, all bounds here ----
    // KC*TROWS*PITCH = 9216 floats = 2304 float4 = exactly 3 per thread.
#pragma unroll
    for (int k = 0; k < 3; ++k) {
      const int f4  = tid + k * NT;           // 0..2303
      const int c   = f4 / 288;               // 288 = TROWS*18
      const int rem = f4 - c * 288;
      const int r   = rem / 18;
      const int cq  = rem - r * 18;
      const int gh  = h0 - S + r;
      const int gw  = w0b - S + cq * 4;
      float4 v = make_float4(0.f, 0.f, 0.f, 0.f);
      if ((unsigned)gh < (unsigned)HH && gw >= 0 && gw + 3 < WW) {
        v = *reinterpret_cast<const float4*>(
              tgt + (((size_t)b * CC + (c0 + c)) * HH + gh) * WW + gw);
      }
      *reinterpret_cast<float4*>(&lds[c][r][cq * 4]) = v;
    }

    // ---- src chunk in registers (same values for all 3 groups; L1 hit) ----
    float srcv[KC][2];
#pragma unroll
    for (int c = 0; c < KC; ++c) {
      const float2 s2 = *reinterpret_cast<const float2*>(
          src + (((size_t)b * CC + (c0 + c)) * HH + h) * WW + w0);
      srcv[c][0] = s2.x; srcv[c][1] = s2.y;
    }

    __syncthreads();

    // ---- compute: 3 di x KC c x (5 ds_read_b64 + 18 FMA) ----
#pragma unroll
    for (int gi = 0; gi < 3; ++gi) {
      const int di  = di_base + gi;         // runtime, wave-uniform
      const int row = ty + S - di;          // in [0,15]
#pragma unroll
      for (int c = 0; c < KC; ++c) {
        const float2* rp =
            reinterpret_cast<const float2*>(&lds[c][row][tx * 2]);
        float win[10];
#pragma unroll
        for (int k = 0; k < 5; ++k) {
          const float2 t = rp[k];
          win[2 * k]     = t.x;
          win[2 * k + 1] = t.y;
        }
#pragma unroll
        for (int dj = -S; dj <= S; ++dj) {
          const int o = gi * 9 + (dj + S);  // compile-time accumulator slot
          acc[o][0] += srcv[c][0] * win[0 + S - dj];
          acc[o][1] += srcv[c][1] * win[1 + S - dj];
        }
      }
    }
  }

  // ---- store: 27 coalesced float2 stores per thread ----
  const size_t HW = (size_t)HH * WW;
  float* op = out + (size_t)b * 81 * HW + (size_t)h * WW + w0;
#pragma unroll
  for (int gi = 0; gi < 3; ++gi) {
    const int di = di_base + gi;            // wave-uniform scalar
#pragma unroll
    for (int dj = -S; dj <= S; ++dj) {
      const int o    = ord_idx(di, dj);     // runtime, cheap scalar epilogue
      const int slot = gi * 9 + (dj + S);
      *reinterpret_cast<float2*>(op + (size_t)o * HW) =
          make_float2(acc[slot][0], acc[slot][1]);
    }
  }
}

extern "C" void kernel_launch(void* const* d_in, const int* in_sizes, int n_in,
                              void* d_out, int out_size, void* d_ws, size_t ws_size,
                              hipStream_t stream) {
  const float* src = (const float*)d_in[0];
  const float* tgt = (const float*)d_in[1];
  float* out = (float*)d_out;
  // search_range (d_in[2]) is fixed at 4 per setup_inputs; geometry hardcoded.
  dim3 grid(WW / TW, HH / TH, BB);   // (4, 16, 8)
  dim3 block(32, TH, NGRP);          // 768 threads
  costvol_kernel<<<grid, block, 0, stream>>>(src, tgt, out);
}